// Round 23
// baseline (350.380 us; speedup 1.0000x reference)
//
#include <hip/hip_runtime.h>
#include <hip/hip_bf16.h>
#include <math.h>

#define B_    500
#define T_    100
#define I_    700
#define HALF_ 350
#define H_    512
#define O_    20
#define M_    (B_*T_)     // 50000
#define BH_   (B_*H_)     // 256000
#define TP_   112         // T padded to 7*16
#define KP_   352         // padded K per phase
#define ASTR2_ 72         // A LDS row stride shorts (144B)
#define ABUF2_ (TP_*ASTR2_) // 8064 shorts per A buffer (64 k-cols + pad)
#define DRB_  116         // dr LDS t-stride BYTES (4-aligned, 29 dwords)
#define NB_   12500       // out_loss blocks (4 (b,t) waves each)

#define START_T  10
#define CODING_T 10
#define REMAIN_T 5

typedef __attribute__((ext_vector_type(8))) short short8v;
typedef __attribute__((ext_vector_type(8))) unsigned short ushort8v;
typedef __attribute__((ext_vector_type(4))) float f32x4;
typedef __attribute__((ext_vector_type(2))) float f32x2;

__device__ __forceinline__ float sigmoidf_(float x) {
  return 1.0f / (1.0f + expf(-x));
}

// HW packed cvt f32x2 -> 2 bf16 (RTNE)
__device__ __forceinline__ unsigned cvtpk(float lo, float hi) {
  unsigned r;
  asm("v_cvt_pk_bf16_f32 %0, %1, %2" : "=v"(r) : "v"(lo), "v"(hi));
  return r;
}

// HW packed cvt 4 f32 -> 4 fp8 e4m3 bytes (t-order), via builtins
__device__ __forceinline__ unsigned cvtpk_fp8x4(float f0, float f1, float f2, float f3) {
  int r = __builtin_amdgcn_cvt_pk_fp8_f32(f0, f1, 0, false);   // bytes 0,1
  r = __builtin_amdgcn_cvt_pk_fp8_f32(f2, f3, r, true);        // bytes 2,3
  return (unsigned)r;
}

__device__ __forceinline__ unsigned short f2bf(float f) {
  unsigned u = __float_as_uint(f);
  u = (u + 0x7fffu + ((u >> 16) & 1u)) >> 16;   // RTNE
  return (unsigned short)u;
}

// source column (in floats) for k-step k; W-side zero padding makes boundary safe
__device__ __forceinline__ int colk(int k) {
  return (k < 11) ? k * 32 : 348 + (k - 11) * 32;
}

// ---------- convert weights + zero the completion counter ----------
__global__ __launch_bounds__(256) void convert_w(
    const float* __restrict__ W1, const float* __restrict__ W2,
    unsigned short* __restrict__ wb, unsigned* __restrict__ counter)
{
  const int idx = blockIdx.x * 256 + threadIdx.x;  // 8-elem chunk; 45056 total
  if (idx == 0) *counter = 0;
  const int ph  = idx / (H_ * (KP_ / 8));
  const int rem = idx % (H_ * (KP_ / 8));
  const int h   = rem / (KP_ / 8);
  const int cc  = (rem % (KP_ / 8)) * 8;
  ushort8v v;
#pragma unroll
  for (int j = 0; j < 8; ++j) {
    const int kk = cc + j;
    float f;
    if (ph == 0) f = (kk < HALF_) ? W1[(size_t)h * HALF_ + kk] : 0.0f;
    else         f = (kk >= 2)    ? W2[(size_t)h * HALF_ + kk - 2] : 0.0f;
    v[j] = f2bf(f);
  }
  *reinterpret_cast<ushort8v*>(wb + (((size_t)ph * H_ + h) * KP_) + cc) = v;
}

// ---------- fused: per-b drive GEMM (r18 structure) + scan w/ ballot pack ----
__global__ __launch_bounds__(1024, 4) void fused_drive_scan(
    const float* __restrict__ input, const unsigned short* __restrict__ Wb,
    const float* __restrict__ v_init, const float* __restrict__ tau_n,
    const float* __restrict__ tau_m, unsigned long long* __restrict__ spkw)
{
  __shared__ __align__(16) unsigned short As[2 * ABUF2_];  // 32256 B
  __shared__ __align__(4) unsigned char d1c[H_ * DRB_];    // 59392 B (fp8)
  __shared__ __align__(4) unsigned char d2c[H_ * DRB_];    // 59392 B (fp8)

  const int tid  = threadIdx.x;
  const int lane = tid & 63;
  const int w    = tid >> 6;           // 0..15
  const int b    = blockIdx.x;         // 0..499

  // A staging: thread tid<896 -> row sr = tid>>3, 4-float chunk c4 = (tid&7)*4
  const int sr = tid >> 3;
  const int c4 = (tid & 7) * 4;
  const bool stLd = (tid < 800);                    // sr < 100
  const bool stZr = (tid >= 800) && (tid < 896);    // pad rows 100..111
  const float* aRowB = input + ((size_t)b * T_ + (stLd ? sr : 0)) * I_ + c4;
  unsigned short* aDstB = As + sr * ASTR2_ + c4;    // + buf (+32 for sub1)

  // B fragment addressing (direct global; Wb is L2-resident)
  const int brow = w * 32 + (lane & 15);
  const int kcS  = (lane >> 4) * 8;
  const unsigned short* bBase0 = Wb + (size_t)brow * KP_ + kcS;
  const unsigned short* bBase1 = Wb + (size_t)(brow + 16) * KP_ + kcS;
  const int arow = lane & 15;

  f32x4 acc[7][2];
#pragma unroll
  for (int i = 0; i < 7; ++i) {
    acc[i][0] = f32x4{0.f, 0.f, 0.f, 0.f};
    acc[i][1] = f32x4{0.f, 0.f, 0.f, 0.f};
  }

  float4 aR0, aR1;
  short8v bC0, bC1, bN0, bN1;

  // ---- prologue ----
  if (stZr) {
    const uint2 z = {0, 0};
    *(uint2*)(aDstB) = z;            *(uint2*)(aDstB + 32) = z;
    *(uint2*)(aDstB + ABUF2_) = z;   *(uint2*)(aDstB + ABUF2_ + 32) = z;
  }
  if (stLd) {
    aR0 = *(const float4*)(aRowB + colk(0));
    aR1 = *(const float4*)(aRowB + colk(1));
  }
  bC0 = *reinterpret_cast<const short8v*>(bBase0);
  bC1 = *reinterpret_cast<const short8v*>(bBase1);
  bN0 = *reinterpret_cast<const short8v*>(bBase0 + 32);
  bN1 = *reinterpret_cast<const short8v*>(bBase1 + 32);
  if (stLd) {
    const uint2 p0 = {cvtpk(aR0.x, aR0.y), cvtpk(aR0.z, aR0.w)};
    const uint2 p1 = {cvtpk(aR1.x, aR1.y), cvtpk(aR1.z, aR1.w)};
    *(uint2*)(aDstB) = p0;
    *(uint2*)(aDstB + 32) = p1;
    aR0 = *(const float4*)(aRowB + colk(2));   // iter-1 windows
    aR1 = *(const float4*)(aRowB + colk(3));
  }
  asm volatile("s_waitcnt lgkmcnt(0)" ::: "memory");
  __builtin_amdgcn_s_barrier();
  asm volatile("" ::: "memory");

#pragma unroll 1
  for (int j = 0; j < 11; ++j) {
    const int buf  = (j & 1) * ABUF2_;
    const int nbuf = ((j + 1) & 1) * ABUF2_;

#pragma unroll
    for (int s = 0; s < 2; ++s) {
      const int k = 2 * j + s;
      // ---- A fragments + MFMA (sub-window s) ----
      short8v a[7];
#pragma unroll
      for (int i = 0; i < 7; ++i)
        a[i] = *reinterpret_cast<const short8v*>(
            As + buf + (arow + i * 16) * ASTR2_ + s * 32 + kcS);
#pragma unroll
      for (int i = 0; i < 7; ++i) {
        acc[i][0] = __builtin_amdgcn_mfma_f32_16x16x32_bf16(a[i], bC0, acc[i][0], 0, 0, 0);
        acc[i][1] = __builtin_amdgcn_mfma_f32_16x16x32_bf16(a[i], bC1, acc[i][1], 0, 0, 0);
      }
      bC0 = bN0; bC1 = bN1;
      if (k < 20) {
        const int kb  = k + 2;
        const int phb = (kb >= 11);
        const size_t bo = (size_t)phb * H_ * KP_ + (kb - phb * 11) * 32;
        bN0 = *reinterpret_cast<const short8v*>(bBase0 + bo);
        bN1 = *reinterpret_cast<const short8v*>(bBase1 + bo);
      }
      // ---- phase boundary: dump acc -> fp8 dr LDS, reset ----
      if (k == 10 || k == 21) {
        unsigned char* ds = (k == 10) ? d1c : d2c;
#pragma unroll
        for (int i = 0; i < 7; ++i) {
          const int tb = i * 16 + ((lane >> 4) << 2);
#pragma unroll
          for (int jj = 0; jj < 2; ++jj) {
            const int hl = w * 32 + jj * 16 + (lane & 15);
            const unsigned r = cvtpk_fp8x4(acc[i][jj][0], acc[i][jj][1],
                                           acc[i][jj][2], acc[i][jj][3]);
            *(unsigned*)(ds + hl * DRB_ + tb) = r;
            acc[i][jj] = f32x4{0.f, 0.f, 0.f, 0.f};
          }
        }
      }
    }

    // ---- stage iter j+1 windows from in-flight aR; load aR for iter j+2 ----
    if (j < 10 && stLd) {
      const uint2 p0 = {cvtpk(aR0.x, aR0.y), cvtpk(aR0.z, aR0.w)};
      const uint2 p1 = {cvtpk(aR1.x, aR1.y), cvtpk(aR1.z, aR1.w)};
      *(uint2*)(aDstB + nbuf) = p0;
      *(uint2*)(aDstB + nbuf + 32) = p1;
      if (j < 9) {
        aR0 = *(const float4*)(aRowB + colk(2 * j + 4));
        aR1 = *(const float4*)(aRowB + colk(2 * j + 5));
      }
    }
    // ---- one drain + one barrier per 2 k-steps ----
    asm volatile("s_waitcnt lgkmcnt(0)" ::: "memory");
    __builtin_amdgcn_s_barrier();
    asm volatile("" ::: "memory");
  }

  // ---- in-block LIF scan: thread = one h; ballot-pack spikes to u64 ----
  if (tid < H_) {
    const int hg = tid;
    const float beta1 = sigmoidf_(tau_n[hg]);
    const float beta2 = sigmoidf_(tau_n[H_ + hg]);
    const float alpha = sigmoidf_(tau_m[hg]);
    const float ob1 = 1.0f - beta1, ob2 = 1.0f - beta2, oa = 1.0f - alpha;

    float d1 = 0.0f, d2 = 0.0f, s = 0.0f;
    float v = v_init[(size_t)b * H_ + hg];
    const unsigned char* r1 = d1c + hg * DRB_;
    const unsigned char* r2 = d2c + hg * DRB_;
    unsigned long long* sw = spkw + (size_t)b * T_ * 8 + w;   // w = wave = h>>6
#pragma unroll 1
    for (int c = 0; c < 25; ++c) {                    // 25 x 4 = 100 steps
      const unsigned u1 = *(const unsigned*)(r1 + c * 4);
      const unsigned u2 = *(const unsigned*)(r2 + c * 4);
      const f32x2 a1 = __builtin_amdgcn_cvt_pk_f32_fp8((int)u1, false);
      const f32x2 b1 = __builtin_amdgcn_cvt_pk_f32_fp8((int)u1, true);
      const f32x2 a2 = __builtin_amdgcn_cvt_pk_f32_fp8((int)u2, false);
      const f32x2 b2 = __builtin_amdgcn_cvt_pk_f32_fp8((int)u2, true);
      const float f1[4] = {a1[0], a1[1], b1[0], b1[1]};
      const float f2[4] = {a2[0], a2[1], b2[0], b2[1]};
#pragma unroll
      for (int jj = 0; jj < 4; ++jj) {
        d1 = beta1 * d1 + ob1 * f1[jj];
        d2 = beta2 * d2 + ob2 * f2[jj];
        v = alpha * v + oa * (d1 + d2) - s;   // V_TH = 1
        const bool spk = (v > 1.0f);
        s = spk ? 1.0f : 0.0f;
        const unsigned long long mball = __ballot(spk);
        if (lane == 0) sw[(size_t)(c * 4 + jj) * 8] = mball;
      }
    }
  }
}

// ---------- output GEMM + loss; LAST block reduces partials ----------
__global__ __launch_bounds__(256) void out_loss(
    const unsigned long long* __restrict__ spkw, const float* __restrict__ Wout,
    const float* __restrict__ bout, const int* __restrict__ target,
    float* __restrict__ oh, float* __restrict__ partials,
    unsigned* __restrict__ counter, float* __restrict__ out, float samples)
{
  const int lane = threadIdx.x & 63;
  const int widx = threadIdx.x >> 6;
  const int bt = blockIdx.x * 4 + widx;          // == b*T_ + t
  const int t = bt % T_;

  // 64B bitpacked row per (b,t): lane l takes byte l -> h = l*8 + j
  const unsigned char* row = (const unsigned char*)(spkw + (size_t)bt * 8);
  const unsigned sbyte = row[lane];

  float acc[O_];
#pragma unroll
  for (int o = 0; o < O_; ++o) acc[o] = 0.0f;

#pragma unroll
  for (int j = 0; j < 8; ++j) {
    if ((sbyte >> j) & 1u) {
      const int hh = lane * 8 + j;
#pragma unroll
      for (int o = 0; o < O_; ++o) acc[o] += Wout[o * H_ + hh];
    }
  }
#pragma unroll
  for (int o = 0; o < O_; ++o) {
#pragma unroll
    for (int off = 32; off; off >>= 1) acc[o] += __shfl_xor(acc[o], off);
    acc[o] += bout[o];
  }
  if (lane < O_) oh[(size_t)bt * O_ + lane] = acc[lane];

  __shared__ float sl[4], sc[4];
  __shared__ unsigned lastFlag;
  float lossc = 0.0f, corr = 0.0f;
  const bool maskv = (t > START_T) && (((t - START_T) % (CODING_T + REMAIN_T)) > REMAIN_T);
  if (maskv) {
    const int tgt = target[bt];
    float m = acc[0];
    int pred = 0;
#pragma unroll
    for (int o = 1; o < O_; ++o) { if (acc[o] > m) { m = acc[o]; pred = o; } }
    float S = 0.0f, etgt = 0.0f;
#pragma unroll
    for (int o = 0; o < O_; ++o) {
      const float eo = expf(acc[o] - m);
      S += eo;
      if (o == tgt) etgt = eo;
    }
    const float inv = 1.0f / S;              // = max(p)
    float S2 = 0.0f;
#pragma unroll
    for (int o = 0; o < O_; ++o) S2 += expf(expf(acc[o] - m) * inv - inv);
    lossc = (inv + logf(S2) - etgt * inv) * (1.0f / (float)B_);
    corr = (pred == tgt) ? 1.0f : 0.0f;
  }
  if (lane == 0) { sl[widx] = lossc; sc[widx] = corr; }
  __syncthreads();
  if (threadIdx.x == 0) {
    partials[blockIdx.x]       = sl[0] + sl[1] + sl[2] + sl[3];
    partials[NB_ + blockIdx.x] = sc[0] + sc[1] + sc[2] + sc[3];
    __threadfence();
    lastFlag = (atomicAdd(counter, 1u) == (unsigned)(NB_ - 1)) ? 1u : 0u;
  }
  __syncthreads();
  if (lastFlag) {
    __threadfence();
    float a = 0.0f, c = 0.0f;
    for (int i = threadIdx.x; i < NB_; i += 256) {
      a += partials[i];
      c += partials[NB_ + i];
    }
    __shared__ float rl[256], rc[256];
    rl[threadIdx.x] = a; rc[threadIdx.x] = c;
    __syncthreads();
    for (int s = 128; s > 0; s >>= 1) {
      if (threadIdx.x < s) {
        rl[threadIdx.x] += rl[threadIdx.x + s];
        rc[threadIdx.x] += rc[threadIdx.x + s];
      }
      __syncthreads();
    }
    if (threadIdx.x == 0) {
      out[0] = rl[0];
      out[1 + (size_t)M_ * O_] = rc[0];
      out[2 + (size_t)M_ * O_] = samples;
    }
  }
}

extern "C" void kernel_launch(void* const* d_in, const int* in_sizes, int n_in,
                              void* d_out, int out_size, void* d_ws, size_t ws_size,
                              hipStream_t stream) {
  const float* input  = (const float*)d_in[0];
  const int*   target = (const int*)d_in[1];
  const float* v_init = (const float*)d_in[2];
  const float* W1     = (const float*)d_in[3];
  const float* W2     = (const float*)d_in[4];
  const float* tau_n  = (const float*)d_in[5];
  const float* tau_m  = (const float*)d_in[6];
  const float* Wout   = (const float*)d_in[7];
  const float* bout   = (const float*)d_in[8];
  float* out = (float*)d_out;
  float* oh  = out + 1;

  // ws layout: Wb[2*512*352 bf16] spkw[500*100*8 u64] partials[2*NB_] counter[1]
  unsigned short* Wb = (unsigned short*)d_ws;
  unsigned long long* spkw = (unsigned long long*)(Wb + (size_t)2 * H_ * KP_);
  float* partials = (float*)(spkw + (size_t)B_ * T_ * 8);
  unsigned* counter = (unsigned*)(partials + 2 * NB_);

  int mcount = 0;
  for (int t = 0; t < T_; ++t)
    if (t > START_T && ((t - START_T) % (CODING_T + REMAIN_T)) > REMAIN_T) mcount++;

  hipLaunchKernelGGL(convert_w, dim3((2 * H_ * KP_ / 8) / 256), dim3(256), 0, stream,
                     W1, W2, Wb, counter);

  hipLaunchKernelGGL(fused_drive_scan, dim3(B_), dim3(1024), 0, stream,
                     input, Wb, v_init, tau_n, tau_m, spkw);

  hipLaunchKernelGGL(out_loss, dim3(NB_), dim3(256), 0, stream,
                     spkw, Wout, bout, target, oh, partials, counter, out,
                     (float)(mcount * B_));
}

// Round 24
// 151.772 us; speedup vs baseline: 2.3086x; 2.3086x over previous
//
#include <hip/hip_runtime.h>
#include <hip/hip_bf16.h>
#include <math.h>

#define B_    500
#define T_    100
#define I_    700
#define HALF_ 350
#define H_    512
#define O_    20
#define M_    (B_*T_)     // 50000
#define BH_   (B_*H_)     // 256000
#define TP_   112         // T padded to 7*16
#define KP_   352         // padded K per phase
#define ASTR2_ 72         // A LDS row stride shorts (144B)
#define ABUF2_ (TP_*ASTR2_) // 8064 shorts per A buffer (64 k-cols + pad)
#define DRB_  116         // dr LDS t-stride BYTES (4-aligned, 29 dwords)
#define NB_   12500       // out_loss blocks (4 (b,t) waves each)

#define START_T  10
#define CODING_T 10
#define REMAIN_T 5

typedef __attribute__((ext_vector_type(8))) short short8v;
typedef __attribute__((ext_vector_type(8))) unsigned short ushort8v;
typedef __attribute__((ext_vector_type(4))) float f32x4;
typedef __attribute__((ext_vector_type(2))) float f32x2;

__device__ __forceinline__ float sigmoidf_(float x) {
  return 1.0f / (1.0f + expf(-x));
}

// HW packed cvt f32x2 -> 2 bf16 (RTNE)
__device__ __forceinline__ unsigned cvtpk(float lo, float hi) {
  unsigned r;
  asm("v_cvt_pk_bf16_f32 %0, %1, %2" : "=v"(r) : "v"(lo), "v"(hi));
  return r;
}

// HW packed cvt 4 f32 -> 4 fp8 e4m3 bytes (t-order), via builtins
__device__ __forceinline__ unsigned cvtpk_fp8x4(float f0, float f1, float f2, float f3) {
  int r = __builtin_amdgcn_cvt_pk_fp8_f32(f0, f1, 0, false);   // bytes 0,1
  r = __builtin_amdgcn_cvt_pk_fp8_f32(f2, f3, r, true);        // bytes 2,3
  return (unsigned)r;
}

__device__ __forceinline__ unsigned short f2bf(float f) {
  unsigned u = __float_as_uint(f);
  u = (u + 0x7fffu + ((u >> 16) & 1u)) >> 16;   // RTNE
  return (unsigned short)u;
}

// source column (in floats) for k-step k; W-side zero padding makes boundary safe
__device__ __forceinline__ int colk(int k) {
  return (k < 11) ? k * 32 : 348 + (k - 11) * 32;
}

// ---------- convert weights fp32 -> padded bf16 Wb[2][512][352] ----------
__global__ __launch_bounds__(256) void convert_w(
    const float* __restrict__ W1, const float* __restrict__ W2,
    unsigned short* __restrict__ wb)
{
  const int idx = blockIdx.x * 256 + threadIdx.x;  // 8-elem chunk; 45056 total
  const int ph  = idx / (H_ * (KP_ / 8));
  const int rem = idx % (H_ * (KP_ / 8));
  const int h   = rem / (KP_ / 8);
  const int cc  = (rem % (KP_ / 8)) * 8;
  ushort8v v;
#pragma unroll
  for (int j = 0; j < 8; ++j) {
    const int kk = cc + j;
    float f;
    if (ph == 0) f = (kk < HALF_) ? W1[(size_t)h * HALF_ + kk] : 0.0f;
    else         f = (kk >= 2)    ? W2[(size_t)h * HALF_ + kk - 2] : 0.0f;
    v[j] = f2bf(f);
  }
  *reinterpret_cast<ushort8v*>(wb + (((size_t)ph * H_ + h) * KP_) + cc) = v;
}

// ---------- fused: per-b drive GEMM (r18 structure + setprio) + scan ----------
__global__ __launch_bounds__(1024, 4) void fused_drive_scan(
    const float* __restrict__ input, const unsigned short* __restrict__ Wb,
    const float* __restrict__ v_init, const float* __restrict__ tau_n,
    const float* __restrict__ tau_m, unsigned char* __restrict__ spikes)
{
  __shared__ __align__(16) unsigned short As[2 * ABUF2_];  // 32256 B
  __shared__ __align__(4) unsigned char d1c[H_ * DRB_];    // 59392 B (fp8)
  __shared__ __align__(4) unsigned char d2c[H_ * DRB_];    // 59392 B (fp8)

  const int tid  = threadIdx.x;
  const int lane = tid & 63;
  const int w    = tid >> 6;           // 0..15
  const int b    = blockIdx.x;         // 0..499

  // A staging: thread tid<896 -> row sr = tid>>3, 4-float chunk c4 = (tid&7)*4
  const int sr = tid >> 3;
  const int c4 = (tid & 7) * 4;
  const bool stLd = (tid < 800);                    // sr < 100
  const bool stZr = (tid >= 800) && (tid < 896);    // pad rows 100..111
  const float* aRowB = input + ((size_t)b * T_ + (stLd ? sr : 0)) * I_ + c4;
  unsigned short* aDstB = As + sr * ASTR2_ + c4;    // + buf (+32 for sub1)

  // B fragment addressing (direct global; Wb is L2-resident)
  const int brow = w * 32 + (lane & 15);
  const int kcS  = (lane >> 4) * 8;
  const unsigned short* bBase0 = Wb + (size_t)brow * KP_ + kcS;
  const unsigned short* bBase1 = Wb + (size_t)(brow + 16) * KP_ + kcS;
  const int arow = lane & 15;

  f32x4 acc[7][2];
#pragma unroll
  for (int i = 0; i < 7; ++i) {
    acc[i][0] = f32x4{0.f, 0.f, 0.f, 0.f};
    acc[i][1] = f32x4{0.f, 0.f, 0.f, 0.f};
  }

  float4 aR0, aR1;
  short8v bC0, bC1, bN0, bN1;

  // ---- prologue ----
  if (stZr) {
    const uint2 z = {0, 0};
    *(uint2*)(aDstB) = z;            *(uint2*)(aDstB + 32) = z;
    *(uint2*)(aDstB + ABUF2_) = z;   *(uint2*)(aDstB + ABUF2_ + 32) = z;
  }
  if (stLd) {
    aR0 = *(const float4*)(aRowB + colk(0));
    aR1 = *(const float4*)(aRowB + colk(1));
  }
  bC0 = *reinterpret_cast<const short8v*>(bBase0);
  bC1 = *reinterpret_cast<const short8v*>(bBase1);
  bN0 = *reinterpret_cast<const short8v*>(bBase0 + 32);
  bN1 = *reinterpret_cast<const short8v*>(bBase1 + 32);
  if (stLd) {
    const uint2 p0 = {cvtpk(aR0.x, aR0.y), cvtpk(aR0.z, aR0.w)};
    const uint2 p1 = {cvtpk(aR1.x, aR1.y), cvtpk(aR1.z, aR1.w)};
    *(uint2*)(aDstB) = p0;
    *(uint2*)(aDstB + 32) = p1;
    aR0 = *(const float4*)(aRowB + colk(2));   // iter-1 windows
    aR1 = *(const float4*)(aRowB + colk(3));
  }
  asm volatile("s_waitcnt lgkmcnt(0)" ::: "memory");
  __builtin_amdgcn_s_barrier();
  asm volatile("" ::: "memory");

#pragma unroll 1
  for (int j = 0; j < 11; ++j) {
    const int buf  = (j & 1) * ABUF2_;
    const int nbuf = ((j + 1) & 1) * ABUF2_;

#pragma unroll
    for (int s = 0; s < 2; ++s) {
      const int k = 2 * j + s;
      // ---- A fragments + MFMA (sub-window s) ----
      short8v a[7];
#pragma unroll
      for (int i = 0; i < 7; ++i)
        a[i] = *reinterpret_cast<const short8v*>(
            As + buf + (arow + i * 16) * ASTR2_ + s * 32 + kcS);
      __builtin_amdgcn_s_setprio(1);
#pragma unroll
      for (int i = 0; i < 7; ++i) {
        acc[i][0] = __builtin_amdgcn_mfma_f32_16x16x32_bf16(a[i], bC0, acc[i][0], 0, 0, 0);
        acc[i][1] = __builtin_amdgcn_mfma_f32_16x16x32_bf16(a[i], bC1, acc[i][1], 0, 0, 0);
      }
      __builtin_amdgcn_s_setprio(0);
      bC0 = bN0; bC1 = bN1;
      if (k < 20) {
        const int kb  = k + 2;
        const int phb = (kb >= 11);
        const size_t bo = (size_t)phb * H_ * KP_ + (kb - phb * 11) * 32;
        bN0 = *reinterpret_cast<const short8v*>(bBase0 + bo);
        bN1 = *reinterpret_cast<const short8v*>(bBase1 + bo);
      }
      // ---- phase boundary: dump acc -> fp8 dr LDS, reset ----
      if (k == 10 || k == 21) {
        unsigned char* ds = (k == 10) ? d1c : d2c;
#pragma unroll
        for (int i = 0; i < 7; ++i) {
          const int tb = i * 16 + ((lane >> 4) << 2);
#pragma unroll
          for (int jj = 0; jj < 2; ++jj) {
            const int hl = w * 32 + jj * 16 + (lane & 15);
            const unsigned r = cvtpk_fp8x4(acc[i][jj][0], acc[i][jj][1],
                                           acc[i][jj][2], acc[i][jj][3]);
            *(unsigned*)(ds + hl * DRB_ + tb) = r;
            acc[i][jj] = f32x4{0.f, 0.f, 0.f, 0.f};
          }
        }
      }
    }

    // ---- stage iter j+1 windows from in-flight aR; load aR for iter j+2 ----
    if (j < 10 && stLd) {
      const uint2 p0 = {cvtpk(aR0.x, aR0.y), cvtpk(aR0.z, aR0.w)};
      const uint2 p1 = {cvtpk(aR1.x, aR1.y), cvtpk(aR1.z, aR1.w)};
      *(uint2*)(aDstB + nbuf) = p0;
      *(uint2*)(aDstB + nbuf + 32) = p1;
      if (j < 9) {
        aR0 = *(const float4*)(aRowB + colk(2 * j + 4));
        aR1 = *(const float4*)(aRowB + colk(2 * j + 5));
      }
    }
    // ---- one drain + one barrier per 2 k-steps ----
    asm volatile("s_waitcnt lgkmcnt(0)" ::: "memory");
    __builtin_amdgcn_s_barrier();
    asm volatile("" ::: "memory");
  }

  // ---- in-block LIF scan: thread = one h column ----
  if (tid < H_) {
    const int hg = tid;
    const float beta1 = sigmoidf_(tau_n[hg]);
    const float beta2 = sigmoidf_(tau_n[H_ + hg]);
    const float alpha = sigmoidf_(tau_m[hg]);
    const float ob1 = 1.0f - beta1, ob2 = 1.0f - beta2, oa = 1.0f - alpha;

    float d1 = 0.0f, d2 = 0.0f, s = 0.0f;
    float v = v_init[(size_t)b * H_ + hg];
    const unsigned char* r1 = d1c + hg * DRB_;
    const unsigned char* r2 = d2c + hg * DRB_;
    unsigned char* sp = spikes + (size_t)b * (T_ * H_) + hg;   // [b][t][h]
#pragma unroll 1
    for (int c = 0; c < 25; ++c) {                    // 25 x 4 = 100 steps
      const unsigned u1 = *(const unsigned*)(r1 + c * 4);
      const unsigned u2 = *(const unsigned*)(r2 + c * 4);
      const f32x2 a1 = __builtin_amdgcn_cvt_pk_f32_fp8((int)u1, false);
      const f32x2 b1 = __builtin_amdgcn_cvt_pk_f32_fp8((int)u1, true);
      const f32x2 a2 = __builtin_amdgcn_cvt_pk_f32_fp8((int)u2, false);
      const f32x2 b2 = __builtin_amdgcn_cvt_pk_f32_fp8((int)u2, true);
      const float f1[4] = {a1[0], a1[1], b1[0], b1[1]};
      const float f2[4] = {a2[0], a2[1], b2[0], b2[1]};
#pragma unroll
      for (int jj = 0; jj < 4; ++jj) {
        d1 = beta1 * d1 + ob1 * f1[jj];
        d2 = beta2 * d2 + ob2 * f2[jj];
        v = alpha * v + oa * (d1 + d2) - s;   // V_TH = 1
        s = (v > 1.0f) ? 1.0f : 0.0f;
        sp[(size_t)(c * 4 + jj) * H_] = (unsigned char)s;
      }
    }
  }
}

// ---------- output GEMM + loss: wave per (b,t), 12500 blocks ----------
__global__ __launch_bounds__(256) void out_loss(
    const unsigned char* __restrict__ spikes, const float* __restrict__ Wout,
    const float* __restrict__ bout, const int* __restrict__ target,
    float* __restrict__ oh, float* __restrict__ partials)
{
  const int lane = threadIdx.x & 63;
  const int widx = threadIdx.x >> 6;
  const int bt = blockIdx.x * 4 + widx;          // == b*T_ + t
  const int t = bt % T_;

  // [b][t][h] layout: row contiguous, 512 B per wave (fully coalesced)
  const uint2 sv = *(const uint2*)(spikes + (size_t)bt * H_ + lane * 8);

  float acc[O_];
#pragma unroll
  for (int o = 0; o < O_; ++o) acc[o] = 0.0f;

#pragma unroll
  for (int j = 0; j < 8; ++j) {
    const unsigned sb = ((j < 4) ? (sv.x >> (8 * j)) : (sv.y >> (8 * (j - 4)))) & 255u;
    if (sb) {
      const int hh = lane * 8 + j;
#pragma unroll
      for (int o = 0; o < O_; ++o) acc[o] += Wout[o * H_ + hh];
    }
  }
  // butterfly: every lane ends with the full sums
#pragma unroll
  for (int o = 0; o < O_; ++o) {
#pragma unroll
    for (int off = 32; off; off >>= 1) acc[o] += __shfl_xor(acc[o], off);
    acc[o] += bout[o];
  }
  if (lane < O_) oh[(size_t)bt * O_ + lane] = acc[lane];

  __shared__ float sl[4], sc[4];
  float lossc = 0.0f, corr = 0.0f;
  const bool maskv = (t > START_T) && (((t - START_T) % (CODING_T + REMAIN_T)) > REMAIN_T);
  if (maskv) {
    // redundant wave-wide softmax (no divergence, no serial-lane section)
    const int tgt = target[bt];
    float m = acc[0];
    int pred = 0;
#pragma unroll
    for (int o = 1; o < O_; ++o) { if (acc[o] > m) { m = acc[o]; pred = o; } }
    float S = 0.0f, etgt = 0.0f;
#pragma unroll
    for (int o = 0; o < O_; ++o) {
      const float eo = expf(acc[o] - m);
      S += eo;
      if (o == tgt) etgt = eo;
    }
    const float inv = 1.0f / S;              // = max(p)
    float S2 = 0.0f;
#pragma unroll
    for (int o = 0; o < O_; ++o) S2 += expf(expf(acc[o] - m) * inv - inv);
    lossc = (inv + logf(S2) - etgt * inv) * (1.0f / (float)B_);
    corr = (pred == tgt) ? 1.0f : 0.0f;
  }
  if (lane == 0) { sl[widx] = lossc; sc[widx] = corr; }
  __syncthreads();
  if (threadIdx.x == 0) {
    partials[blockIdx.x]       = sl[0] + sl[1] + sl[2] + sl[3];
    partials[NB_ + blockIdx.x] = sc[0] + sc[1] + sc[2] + sc[3];
  }
}

__global__ __launch_bounds__(256) void loss_final(
    const float* __restrict__ partials, float* __restrict__ out, float samples)
{
  float a = 0.0f, c = 0.0f;
  for (int i = threadIdx.x; i < NB_; i += 256) { a += partials[i]; c += partials[NB_ + i]; }
  __shared__ float sl[256], sc[256];
  sl[threadIdx.x] = a; sc[threadIdx.x] = c;
  __syncthreads();
  for (int s = 128; s > 0; s >>= 1) {
    if (threadIdx.x < s) {
      sl[threadIdx.x] += sl[threadIdx.x + s];
      sc[threadIdx.x] += sc[threadIdx.x + s];
    }
    __syncthreads();
  }
  if (threadIdx.x == 0) {
    out[0] = sl[0];
    out[1 + (size_t)M_ * O_] = sc[0];
    out[2 + (size_t)M_ * O_] = samples;
  }
}

extern "C" void kernel_launch(void* const* d_in, const int* in_sizes, int n_in,
                              void* d_out, int out_size, void* d_ws, size_t ws_size,
                              hipStream_t stream) {
  const float* input  = (const float*)d_in[0];
  const int*   target = (const int*)d_in[1];
  const float* v_init = (const float*)d_in[2];
  const float* W1     = (const float*)d_in[3];
  const float* W2     = (const float*)d_in[4];
  const float* tau_n  = (const float*)d_in[5];
  const float* tau_m  = (const float*)d_in[6];
  const float* Wout   = (const float*)d_in[7];
  const float* bout   = (const float*)d_in[8];
  float* out = (float*)d_out;
  float* oh  = out + 1;

  // ws layout: Wb[2*512*352 bf16] spikes[500*100*512 u8] partials[2*NB_ f32]
  unsigned short* Wb = (unsigned short*)d_ws;
  unsigned char* spikes = (unsigned char*)(Wb + (size_t)2 * H_ * KP_);
  float* partials = (float*)(spikes + (size_t)B_ * T_ * H_);

  hipLaunchKernelGGL(convert_w, dim3((2 * H_ * KP_ / 8) / 256), dim3(256), 0, stream,
                     W1, W2, Wb);

  hipLaunchKernelGGL(fused_drive_scan, dim3(B_), dim3(1024), 0, stream,
                     input, Wb, v_init, tau_n, tau_m, spikes);

  hipLaunchKernelGGL(out_loss, dim3(NB_), dim3(256), 0, stream,
                     spikes, Wout, bout, target, oh, partials);

  int mcount = 0;
  for (int t = 0; t < T_; ++t)
    if (t > START_T && ((t - START_T) % (CODING_T + REMAIN_T)) > REMAIN_T) mcount++;
  hipLaunchKernelGGL(loss_final, dim3(1), dim3(256), 0, stream, partials,
                     out, (float)(mcount * B_));
}